// Round 17
// baseline (209.596 us; speedup 1.0000x reference)
//
#include <hip/hip_runtime.h>

#define EPSF 1e-9f

typedef __bf16 bf16x8 __attribute__((ext_vector_type(8)));
typedef float  f32x4  __attribute__((ext_vector_type(4)));
typedef unsigned short ushort_t;
typedef unsigned int uint_t;
typedef ushort_t us8 __attribute__((ext_vector_type(8)));

__device__ __forceinline__ float2 cmul(float cr, float ci, float2 v) {
    return make_float2(cr * v.x - ci * v.y, ci * v.x + cr * v.y);
}

__device__ __forceinline__ ushort_t f2bf(float f) {
    unsigned int u = __float_as_uint(f);
    u += 0x7FFFu + ((u >> 16) & 1u);   // RNE
    return (ushort_t)(u >> 16);
}

__device__ __forceinline__ ushort_t f2bf_hw(float f) {   // native RNE cvt
    __bf16 b = (__bf16)f;
    return *(ushort_t*)&b;
}

// packed pair helpers: low 16 bits = element 2p, high = 2p+1
__device__ __forceinline__ float2 bfu2(uint_t u) {
    return make_float2(__uint_as_float(u << 16), __uint_as_float(u & 0xFFFF0000u));
}
__device__ __forceinline__ uint_t packbf(float2 v) {
    return ((uint_t)f2bf(v.y) << 16) | (uint_t)f2bf(v.x);
}

// ---------------- init: zero cnt + lambda tables (block 0) ----------------
__global__ void k_init(const float* __restrict__ ldt, const float* __restrict__ llr,
                       const float* __restrict__ lim, float* __restrict__ tab,
                       int* __restrict__ cnt, int N) {
    int i = blockIdx.x * blockDim.x + threadIdx.x;
    if (i < N) cnt[i] = 0;
    if (blockIdx.x == 0 && threadIdx.x < 64) {
        int p = threadIdx.x;
        float dt  = expf(ldt[0]);
        float mag = expf(-expf(llr[p]) * dt);
        float ph  = lim[p] * dt;
        float c = cosf(ph), s = sinf(ph);
        float m2 = mag * mag, m3 = m2 * mag;
        float c2 = c * c - s * s, s2 = 2.f * c * s;
        float c3 = c2 * c - s2 * s, s3 = s2 * c + c2 * s;
        tab[p]        = c * mag;          tab[64 + p]  = s * mag;          // L1
        tab[128 + p]  = c * (1.f - mag);  tab[192 + p] = s * (1.f - mag);  // O1
        tab[256 + p]  = c2 * m2;          tab[320 + p] = s2 * m2;          // L2
        tab[384 + p]  = c3 * m3;          tab[448 + p] = s3 * m3;          // L3
    }
}

// ---------------- prep: all 3 weights -> bf16 B-fragment layout, one launch ----------------
__global__ void k_prepw3(const float* __restrict__ W1, const float* __restrict__ W2,
                         const float* __restrict__ Wp, ushort_t* __restrict__ wb1,
                         ushort_t* __restrict__ wb2, ushort_t* __restrict__ wpb) {
    int tid = blockIdx.x * blockDim.x + threadIdx.x;
    const float* w; ushort_t* wb; int ncols, nsteps;
    if (tid < 4096)       { w = W1; wb = wb1; ncols = 256; nsteps = 4; }
    else if (tid < 8192)  { tid -= 4096; w = W2; wb = wb2; ncols = 256; nsteps = 4; }
    else                  { tid -= 8192; w = Wp; wb = wpb; ncols = 128; nsteps = 8; }
    int l  = tid & 63;
    int s  = (tid >> 6) % nsteps;
    int nt = tid / (64 * nsteps);
    int col = nt * 16 + (l & 15);
    int kb  = s * 32 + (l >> 4) * 8;
    us8 d;
#pragma unroll
    for (int j = 0; j < 8; ++j) d[j] = f2bf(w[(size_t)(kb + j) * ncols + col]);
    *(us8*)(wb + (size_t)tid * 8) = d;
}

// ---------------- MFMA fused MLP -> bf16 xpb (4 m-tiles/block, weight reuse x4) ----------------
__global__ void __launch_bounds__(256)
k_mlpf(const float* __restrict__ x, const ushort_t* __restrict__ wb1,
       const ushort_t* __restrict__ wb2, const ushort_t* __restrict__ wpb,
       const float* __restrict__ bp, ushort_t* __restrict__ xpb, int Mt) {
    __shared__ ushort_t hs[4][4096];   // 32KB: 4 m-tiles x 16x256 bf16 H (swizzled), block-shared
    const int wid = threadIdx.x >> 6, l = threadIdx.x & 63;
    const int mt0 = blockIdx.x * 4;
    const int llo = l & 15, lhi = l >> 4;

    // A fragments for 4 m-tiles (K=128 -> 4 ksteps); tail clamps to last row block
    bf16x8 af[4][4];
#pragma unroll
    for (int m = 0; m < 4; ++m) {
        int mt = mt0 + m; if (mt >= Mt) mt = Mt - 1;
        const float* xr = x + (size_t)(mt * 16 + llo) * 128 + lhi * 8;
#pragma unroll
        for (int s = 0; s < 4; ++s) {
            float4 v0 = *(const float4*)(xr + s * 32);
            float4 v1 = *(const float4*)(xr + s * 32 + 4);
            __bf16 d[8];
            d[0] = (__bf16)v0.x; d[1] = (__bf16)v0.y; d[2] = (__bf16)v0.z; d[3] = (__bf16)v0.w;
            d[4] = (__bf16)v1.x; d[5] = (__bf16)v1.y; d[6] = (__bf16)v1.z; d[7] = (__bf16)v1.w;
            af[m][s] = *(bf16x8*)d;
        }
    }

    const bf16x8* B1 = (const bf16x8*)wb1;
    const bf16x8* B2 = (const bf16x8*)wb2;
    const bf16x8* BP = (const bf16x8*)wpb;
    const f32x4 zero = {0.f, 0.f, 0.f, 0.f};

    // ---- Phase 1: GEMM1/2 + silu; wave w owns nt = 4w..4w+3, all 4 m-tiles ----
#pragma unroll
    for (int j = 0; j < 4; ++j) {
        int nt = wid * 4 + j;
        bf16x8 b1[4], b2[4];
#pragma unroll
        for (int s = 0; s < 4; ++s) {
            b1[s] = B1[(nt * 4 + s) * 64 + l];
            b2[s] = B2[(nt * 4 + s) * 64 + l];
        }
#pragma unroll
        for (int m = 0; m < 4; ++m) {
            f32x4 a1 = zero, a2 = zero;
#pragma unroll
            for (int s = 0; s < 4; ++s) {
                a1 = __builtin_amdgcn_mfma_f32_16x16x32_bf16(af[m][s], b1[s], a1, 0, 0, 0);
                a2 = __builtin_amdgcn_mfma_f32_16x16x32_bf16(af[m][s], b2[s], a2, 0, 0, 0);
            }
#pragma unroll
            for (int i = 0; i < 4; ++i) {
                float g = a1[i];
                float hv = g * __builtin_amdgcn_rcpf(1.f + __expf(-g)) * a2[i];
                int r = 4 * lhi + i;
                int byte = (r << 9) + ((nt * 16 + llo) << 1);  // row stride 512B (256 bf16)
                byte ^= (r & 7) << 4;
                hs[m][byte >> 1] = f2bf_hw(hv);
            }
        }
    }
    __syncthreads();

    // ---- Phase 2: GEMM3 over K=256; wave w owns nt3 = 2w, 2w+1, all 4 m-tiles ----
#pragma unroll
    for (int j = 0; j < 2; ++j) {
        int nt3 = wid * 2 + j;
        f32x4 acc0 = zero, acc1 = zero, acc2 = zero, acc3 = zero;
#pragma unroll
        for (int sg = 0; sg < 8; ++sg) {
            bf16x8 bw = BP[(nt3 * 8 + sg) * 64 + l];
            int byte = (llo << 9) + (sg << 6) + (lhi << 4);
            byte ^= (llo & 7) << 4;
            bf16x8 h0 = *(const bf16x8*)((const char*)hs[0] + byte);
            acc0 = __builtin_amdgcn_mfma_f32_16x16x32_bf16(h0, bw, acc0, 0, 0, 0);
            bf16x8 h1 = *(const bf16x8*)((const char*)hs[1] + byte);
            acc1 = __builtin_amdgcn_mfma_f32_16x16x32_bf16(h1, bw, acc1, 0, 0, 0);
            bf16x8 h2 = *(const bf16x8*)((const char*)hs[2] + byte);
            acc2 = __builtin_amdgcn_mfma_f32_16x16x32_bf16(h2, bw, acc2, 0, 0, 0);
            bf16x8 h3 = *(const bf16x8*)((const char*)hs[3] + byte);
            acc3 = __builtin_amdgcn_mfma_f32_16x16x32_bf16(h3, bw, acc3, 0, 0, 0);
        }
        float bpv = bp[nt3 * 16 + llo];
        f32x4 accs[4] = {acc0, acc1, acc2, acc3};
#pragma unroll
        for (int m = 0; m < 4; ++m) {
            if (mt0 + m < Mt) {
                const int row0 = (mt0 + m) * 16;
#pragma unroll
                for (int i = 0; i < 4; ++i) {
                    int r = row0 + 4 * lhi + i;
                    xpb[(size_t)r * 128 + nt3 * 16 + llo] = f2bf_hw(accs[m][i] + bpv);
                }
            }
        }
    }
}

// ---------------- CSR build (by dst). in-deg == out-deg for this edge list ----------------
__global__ void k_hist(const int* __restrict__ ei, int E, int* __restrict__ cnt) {
    int e = blockIdx.x * blockDim.x + threadIdx.x;
    if (e < E) atomicAdd(&cnt[ei[E + e]], 1);      // histogram over dst
}

__global__ void __launch_bounds__(256)
k_scanA(const int* __restrict__ cnt, int N, int* __restrict__ bsum) {
    __shared__ int s[256];
    int t = threadIdx.x;
    int i = blockIdx.x * 256 + t;
    int v = (i < N) ? cnt[i] : 0;
    s[t] = v;
    __syncthreads();
#pragma unroll
    for (int d = 128; d > 0; d >>= 1) {
        if (t < d) s[t] += s[t + d];
        __syncthreads();
    }
    if (t == 0) bsum[blockIdx.x] = s[0];
}

__global__ void __launch_bounds__(1024)
k_scanB(const int* __restrict__ bsum, int NB, int* __restrict__ bpre,
        int* __restrict__ offN) {
    __shared__ int s[1024];
    int t = threadIdx.x;
    int v = (t < NB) ? bsum[t] : 0;
    s[t] = v;
    __syncthreads();
    for (int d = 1; d < 1024; d <<= 1) {
        int u = (t >= d) ? s[t - d] : 0;
        __syncthreads();
        s[t] += u;
        __syncthreads();
    }
    if (t < NB) bpre[t] = s[t] - v;          // exclusive
    if (t == NB - 1) *offN = s[t];           // total
}

__global__ void __launch_bounds__(256)
k_scanC(const int* __restrict__ cnt, int N, const int* __restrict__ bpre,
        int* __restrict__ off, int* __restrict__ cursor, float* __restrict__ bv) {
    __shared__ int s[256];
    int t = threadIdx.x;
    int i = blockIdx.x * 256 + t;
    int v = (i < N) ? cnt[i] : 0;
    s[t] = v;
    __syncthreads();
    for (int d = 1; d < 256; d <<= 1) {
        int u = (t >= d) ? s[t - d] : 0;
        __syncthreads();
        s[t] += u;
        __syncthreads();
    }
    if (i < N) {
        int excl = bpre[blockIdx.x] + s[t] - v;
        off[i] = excl;
        cursor[i] = excl;
        bv[i] = (v > 1) ? (-1.f / ((float)v - 1.f + EPSF)) : 0.f;
    }
}

// fill packed edge records: (src, bv[src]) -> one 8B load per edge in the passes
__global__ void k_fill(const int* __restrict__ ei, int E, const float* __restrict__ bv,
                       int* __restrict__ cursor, uint2* __restrict__ csrb) {
    int e = blockIdx.x * blockDim.x + threadIdx.x;
    if (e < E) {
        int s = ei[e], d = ei[E + e];
        int p = atomicAdd(&cursor[d], 1);
        csrb[p] = make_uint2((uint_t)s, __float_as_uint(bv[s]));
    }
}

// ---------------- fused gather + node passes (HALF-WAVE per node, uint2 loads, x4 unroll) ----------------
// lane ll in [0,32): owns complex pairs p0=2*ll, p1=2*ll+1 (uint2 per table row).

__global__ void __launch_bounds__(256)
k_passA(const ushort_t* __restrict__ xpb, const uint2* __restrict__ eb,
        const int* __restrict__ off, const float* __restrict__ tab,
        ushort_t* __restrict__ Xbb, ushort_t* __restrict__ a1b, int N) {
    int tid = blockIdx.x * blockDim.x + threadIdx.x;
    int v = tid >> 5, ll = tid & 31;
    if (v >= N) return;
    int beg = off[v], end = off[v + 1];
    float2 m00 = {0.f,0.f}, m01 = {0.f,0.f}, xb0 = {0.f,0.f}, xb1 = {0.f,0.f};
    const uint2* tb = (const uint2*)xpb;   // row stride 32 uint2
    int k = beg;
    for (; k + 3 < end; k += 4) {
        uint2 e0 = eb[k], e1 = eb[k+1], e2 = eb[k+2], e3 = eb[k+3];
        uint2 u0 = tb[(size_t)e0.x * 32 + ll];
        uint2 u1 = tb[(size_t)e1.x * 32 + ll];
        uint2 u2 = tb[(size_t)e2.x * 32 + ll];
        uint2 u3 = tb[(size_t)e3.x * 32 + ll];
        float b0 = __uint_as_float(e0.y), b1 = __uint_as_float(e1.y);
        float b2 = __uint_as_float(e2.y), b3 = __uint_as_float(e3.y);
        float2 t00=bfu2(u0.x), t01=bfu2(u0.y), t10=bfu2(u1.x), t11=bfu2(u1.y);
        float2 t20=bfu2(u2.x), t21=bfu2(u2.y), t30=bfu2(u3.x), t31=bfu2(u3.y);
        m00.x += (t00.x+t10.x)+(t20.x+t30.x); m00.y += (t00.y+t10.y)+(t20.y+t30.y);
        m01.x += (t01.x+t11.x)+(t21.x+t31.x); m01.y += (t01.y+t11.y)+(t21.y+t31.y);
        xb0.x += b0*t00.x + b1*t10.x + b2*t20.x + b3*t30.x;
        xb0.y += b0*t00.y + b1*t10.y + b2*t20.y + b3*t30.y;
        xb1.x += b0*t01.x + b1*t11.x + b2*t21.x + b3*t31.x;
        xb1.y += b0*t01.y + b1*t11.y + b2*t21.y + b3*t31.y;
    }
    for (; k < end; ++k) {
        uint2 e0 = eb[k];
        uint2 u0 = tb[(size_t)e0.x * 32 + ll];
        float b0 = __uint_as_float(e0.y);
        float2 t00=bfu2(u0.x), t01=bfu2(u0.y);
        m00.x += t00.x; m00.y += t00.y; m01.x += t01.x; m01.y += t01.y;
        xb0.x += b0*t00.x; xb0.y += b0*t00.y;
        xb1.x += b0*t01.x; xb1.y += b0*t01.y;
    }
    ((uint2*)Xbb)[(size_t)v * 32 + ll] = make_uint2(packbf(xb0), packbf(xb1));
    uint2 xvu = tb[(size_t)v * 32 + ll];
    float2 xv0 = bfu2(xvu.x), xv1 = bfu2(xvu.y);
    int dg = end - beg;
    int p0 = 2 * ll, p1 = p0 + 1;
    float Q = 1.f / ((float)dg - 1.f + EPSF);
    float2 a0, a1v;
    {
        float L1r=tab[p0], L1i=tab[64+p0], O1r=tab[128+p0], O1i=tab[192+p0];
        float2 t1 = cmul(O1r,O1i,xv0), t2 = cmul(L1r,L1i,m00);
        a0 = make_float2(t1.x + Q*t2.x, t1.y + Q*t2.y);
        if (dg == 1) a0 = xv0;
    }
    {
        float L1r=tab[p1], L1i=tab[64+p1], O1r=tab[128+p1], O1i=tab[192+p1];
        float2 t1 = cmul(O1r,O1i,xv1), t2 = cmul(L1r,L1i,m01);
        a1v = make_float2(t1.x + Q*t2.x, t1.y + Q*t2.y);
        if (dg == 1) a1v = xv1;
    }
    ((uint2*)a1b)[(size_t)v * 32 + ll] = make_uint2(packbf(a0), packbf(a1v));
}

__global__ void __launch_bounds__(256)
k_passB(const ushort_t* __restrict__ xpb, const ushort_t* __restrict__ a1b,
        const uint2* __restrict__ eb, const int* __restrict__ off,
        const float* __restrict__ tab, ushort_t* __restrict__ ab1b,
        float* __restrict__ Bv, float* __restrict__ B2v,
        ushort_t* __restrict__ a2b, int N) {
    int tid = blockIdx.x * blockDim.x + threadIdx.x;
    int v = tid >> 5, ll = tid & 31;
    if (v >= N) return;
    int beg = off[v], end = off[v + 1];
    float2 A10 = {0.f,0.f}, A11 = {0.f,0.f}, ab0 = {0.f,0.f}, ab1 = {0.f,0.f};
    float Bs = 0.f, B2s = 0.f;
    const uint2* tb = (const uint2*)a1b;
    int k = beg;
    for (; k + 3 < end; k += 4) {
        uint2 e0 = eb[k], e1 = eb[k+1], e2 = eb[k+2], e3 = eb[k+3];
        uint2 u0 = tb[(size_t)e0.x * 32 + ll];
        uint2 u1 = tb[(size_t)e1.x * 32 + ll];
        uint2 u2 = tb[(size_t)e2.x * 32 + ll];
        uint2 u3 = tb[(size_t)e3.x * 32 + ll];
        float b0 = __uint_as_float(e0.y), b1 = __uint_as_float(e1.y);
        float b2 = __uint_as_float(e2.y), b3 = __uint_as_float(e3.y);
        float2 t00=bfu2(u0.x), t01=bfu2(u0.y), t10=bfu2(u1.x), t11=bfu2(u1.y);
        float2 t20=bfu2(u2.x), t21=bfu2(u2.y), t30=bfu2(u3.x), t31=bfu2(u3.y);
        A10.x += (t00.x+t10.x)+(t20.x+t30.x); A10.y += (t00.y+t10.y)+(t20.y+t30.y);
        A11.x += (t01.x+t11.x)+(t21.x+t31.x); A11.y += (t01.y+t11.y)+(t21.y+t31.y);
        ab0.x += b0*t00.x + b1*t10.x + b2*t20.x + b3*t30.x;
        ab0.y += b0*t00.y + b1*t10.y + b2*t20.y + b3*t30.y;
        ab1.x += b0*t01.x + b1*t11.x + b2*t21.x + b3*t31.x;
        ab1.y += b0*t01.y + b1*t11.y + b2*t21.y + b3*t31.y;
        Bs += (b0 + b1) + (b2 + b3);
        B2s += (b0*b0 + b1*b1) + (b2*b2 + b3*b3);
    }
    for (; k < end; ++k) {
        uint2 e0 = eb[k];
        uint2 u0 = tb[(size_t)e0.x * 32 + ll];
        float b0 = __uint_as_float(e0.y);
        float2 t00=bfu2(u0.x), t01=bfu2(u0.y);
        A10.x += t00.x; A10.y += t00.y; A11.x += t01.x; A11.y += t01.y;
        ab0.x += b0*t00.x; ab0.y += b0*t00.y;
        ab1.x += b0*t01.x; ab1.y += b0*t01.y;
        Bs += b0; B2s += b0*b0;
    }
    ((uint2*)ab1b)[(size_t)v * 32 + ll] = make_uint2(packbf(ab0), packbf(ab1));
    if (ll == 0) { Bv[v] = Bs; B2v[v] = B2s; }
    uint2 xvu = ((const uint2*)xpb)[(size_t)v * 32 + ll];
    float2 xv0 = bfu2(xvu.x), xv1 = bfu2(xvu.y);
    int dg = end - beg;
    int p0 = 2 * ll, p1 = p0 + 1;
    float Q = 1.f / ((float)dg - 1.f + EPSF);
    float2 a0, a1v;
    {
        float L1r=tab[p0], L1i=tab[64+p0], O1r=tab[128+p0], O1i=tab[192+p0];
        float2 lx = cmul(L1r,L1i,xv0);
        float2 m1 = make_float2(A10.x + Bs*lx.x, A10.y + Bs*lx.y);
        float2 t1 = cmul(O1r,O1i,xv0), lm = cmul(L1r,L1i,m1);
        a0 = make_float2(t1.x + Q*lm.x, t1.y + Q*lm.y);
        if (dg == 1) a0 = xv0;
    }
    {
        float L1r=tab[p1], L1i=tab[64+p1], O1r=tab[128+p1], O1i=tab[192+p1];
        float2 lx = cmul(L1r,L1i,xv1);
        float2 m1 = make_float2(A11.x + Bs*lx.x, A11.y + Bs*lx.y);
        float2 t1 = cmul(O1r,O1i,xv1), lm = cmul(L1r,L1i,m1);
        a1v = make_float2(t1.x + Q*lm.x, t1.y + Q*lm.y);
        if (dg == 1) a1v = xv1;
    }
    ((uint2*)a2b)[(size_t)v * 32 + ll] = make_uint2(packbf(a0), packbf(a1v));
}

__global__ void __launch_bounds__(256)
k_passC(const ushort_t* __restrict__ xpb, const ushort_t* __restrict__ a2b,
        const ushort_t* __restrict__ a1b, const ushort_t* __restrict__ Xbb,
        const float* __restrict__ bv, const float* __restrict__ Bv,
        const uint2* __restrict__ eb, const int* __restrict__ off,
        const float* __restrict__ tab, ushort_t* __restrict__ a3b, int N) {
    int tid = blockIdx.x * blockDim.x + threadIdx.x;
    int v = tid >> 5, ll = tid & 31;
    if (v >= N) return;
    int beg = off[v], end = off[v + 1];
    float2 A20 = {0.f,0.f}, A21 = {0.f,0.f};
    const uint2* tb = (const uint2*)a2b;
    int k = beg;
    for (; k + 3 < end; k += 4) {
        uint2 u0 = tb[(size_t)eb[k].x * 32 + ll];
        uint2 u1 = tb[(size_t)eb[k+1].x * 32 + ll];
        uint2 u2 = tb[(size_t)eb[k+2].x * 32 + ll];
        uint2 u3 = tb[(size_t)eb[k+3].x * 32 + ll];
        float2 t00=bfu2(u0.x), t01=bfu2(u0.y), t10=bfu2(u1.x), t11=bfu2(u1.y);
        float2 t20=bfu2(u2.x), t21=bfu2(u2.y), t30=bfu2(u3.x), t31=bfu2(u3.y);
        A20.x += (t00.x+t10.x)+(t20.x+t30.x); A20.y += (t00.y+t10.y)+(t20.y+t30.y);
        A21.x += (t01.x+t11.x)+(t21.x+t31.x); A21.y += (t01.y+t11.y)+(t21.y+t31.y);
    }
    for (; k < end; ++k) {
        uint2 u0 = tb[(size_t)eb[k].x * 32 + ll];
        float2 t00=bfu2(u0.x), t01=bfu2(u0.y);
        A20.x += t00.x; A20.y += t00.y; A21.x += t01.x; A21.y += t01.y;
    }
    size_t vo = (size_t)v * 32 + ll;
    uint2 xvu = ((const uint2*)xpb)[vo];
    uint2 a1u = ((const uint2*)a1b)[vo];
    uint2 xbu = ((const uint2*)Xbb)[vo];
    float2 xv0 = bfu2(xvu.x), xv1 = bfu2(xvu.y);
    float2 a10 = bfu2(a1u.x), a11 = bfu2(a1u.y);
    float2 Xb0 = bfu2(xbu.x), Xb1 = bfu2(xbu.y);
    int dg = end - beg;
    float Bs = Bv[v], bs = bv[v];
    int p0 = 2 * ll, p1 = p0 + 1;
    float Q = 1.f / ((float)dg - 1.f + EPSF);
    float2 a0, a1vv;
    {
        float L1r=tab[p0], L1i=tab[64+p0], O1r=tab[128+p0], O1i=tab[192+p0];
        float L2r=tab[256+p0], L2i=tab[320+p0];
        float2 la1 = cmul(L1r,L1i,a10), lxb = cmul(L2r,L2i,Xb0);
        float2 m2 = make_float2(A20.x + Bs*la1.x + bs*lxb.x,
                                A20.y + Bs*la1.y + bs*lxb.y);
        float2 t1 = cmul(O1r,O1i,xv0), lm = cmul(L1r,L1i,m2);
        a0 = make_float2(t1.x + Q*lm.x, t1.y + Q*lm.y);
        if (dg == 1) a0 = xv0;
    }
    {
        float L1r=tab[p1], L1i=tab[64+p1], O1r=tab[128+p1], O1i=tab[192+p1];
        float L2r=tab[256+p1], L2i=tab[320+p1];
        float2 la1 = cmul(L1r,L1i,a11), lxb = cmul(L2r,L2i,Xb1);
        float2 m2 = make_float2(A21.x + Bs*la1.x + bs*lxb.x,
                                A21.y + Bs*la1.y + bs*lxb.y);
        float2 t1 = cmul(O1r,O1i,xv1), lm = cmul(L1r,L1i,m2);
        a1vv = make_float2(t1.x + Q*lm.x, t1.y + Q*lm.y);
        if (dg == 1) a1vv = xv1;
    }
    ((uint2*)a3b)[vo] = make_uint2(packbf(a0), packbf(a1vv));
}

__global__ void __launch_bounds__(256)
k_passD(const float* __restrict__ xin, const ushort_t* __restrict__ xpb,
        const ushort_t* __restrict__ a3b, const ushort_t* __restrict__ a2b,
        const ushort_t* __restrict__ ab1b, const float* __restrict__ bv,
        const float* __restrict__ Bv, const float* __restrict__ B2v,
        const uint2* __restrict__ eb, const int* __restrict__ off,
        const float* __restrict__ tab, float* __restrict__ out, int N) {
    int tid = blockIdx.x * blockDim.x + threadIdx.x;
    int v = tid >> 5, ll = tid & 31;
    if (v >= N) return;
    int beg = off[v], end = off[v + 1];
    float2 A30 = {0.f,0.f}, A31 = {0.f,0.f};
    const uint2* tb = (const uint2*)a3b;
    int k = beg;
    for (; k + 3 < end; k += 4) {
        uint2 u0 = tb[(size_t)eb[k].x * 32 + ll];
        uint2 u1 = tb[(size_t)eb[k+1].x * 32 + ll];
        uint2 u2 = tb[(size_t)eb[k+2].x * 32 + ll];
        uint2 u3 = tb[(size_t)eb[k+3].x * 32 + ll];
        float2 t00=bfu2(u0.x), t01=bfu2(u0.y), t10=bfu2(u1.x), t11=bfu2(u1.y);
        float2 t20=bfu2(u2.x), t21=bfu2(u2.y), t30=bfu2(u3.x), t31=bfu2(u3.y);
        A30.x += (t00.x+t10.x)+(t20.x+t30.x); A30.y += (t00.y+t10.y)+(t20.y+t30.y);
        A31.x += (t01.x+t11.x)+(t21.x+t31.x); A31.y += (t01.y+t11.y)+(t21.y+t31.y);
    }
    for (; k < end; ++k) {
        uint2 u0 = tb[(size_t)eb[k].x * 32 + ll];
        float2 t00=bfu2(u0.x), t01=bfu2(u0.y);
        A30.x += t00.x; A30.y += t00.y; A31.x += t01.x; A31.y += t01.y;
    }
    size_t vo = (size_t)v * 32 + ll;
    uint2 xvu = ((const uint2*)xpb)[vo];
    uint2 a2u = ((const uint2*)a2b)[vo];
    uint2 abu = ((const uint2*)ab1b)[vo];
    float2 xv0 = bfu2(xvu.x), xv1 = bfu2(xvu.y);
    float2 a20 = bfu2(a2u.x), a21 = bfu2(a2u.y);
    float2 Ab0 = bfu2(abu.x), Ab1v = bfu2(abu.y);
    int dg = end - beg;
    float Bs = Bv[v], bs = bv[v], B2s = B2v[v];
    float bB2 = bs * B2s;
    int p0 = 2 * ll, p1 = p0 + 1;
    float2 g0, g1;
    {
        float L1r=tab[p0], L1i=tab[64+p0], O1r=tab[128+p0], O1i=tab[192+p0];
        float L2r=tab[256+p0], L2i=tab[320+p0], L3r=tab[384+p0], L3i=tab[448+p0];
        float2 la2 = cmul(L1r,L1i,a20), lab = cmul(L2r,L2i,Ab0), lx3 = cmul(L3r,L3i,xv0);
        float2 m3 = make_float2(A30.x + Bs*la2.x + bs*lab.x + bB2*lx3.x,
                                A30.y + Bs*la2.y + bs*lab.y + bB2*lx3.y);
        if (dg == 0) {
            g0 = xv0;
        } else {
            float inv = 1.f / ((float)dg + EPSF);
            float2 t1 = cmul(O1r,O1i,xv0), lm = cmul(L1r,L1i,m3);
            g0 = make_float2(t1.x + lm.x*inv, t1.y + lm.y*inv);
        }
    }
    {
        float L1r=tab[p1], L1i=tab[64+p1], O1r=tab[128+p1], O1i=tab[192+p1];
        float L2r=tab[256+p1], L2i=tab[320+p1], L3r=tab[384+p1], L3i=tab[448+p1];
        float2 la2 = cmul(L1r,L1i,a21), lab = cmul(L2r,L2i,Ab1v), lx3 = cmul(L3r,L3i,xv1);
        float2 m3 = make_float2(A31.x + Bs*la2.x + bs*lab.x + bB2*lx3.x,
                                A31.y + Bs*la2.y + bs*lab.y + bB2*lx3.y);
        if (dg == 0) {
            g1 = xv1;
        } else {
            float inv = 1.f / ((float)dg + EPSF);
            float2 t1 = cmul(O1r,O1i,xv1), lm = cmul(L1r,L1i,m3);
            g1 = make_float2(t1.x + lm.x*inv, t1.y + lm.y*inv);
        }
    }
    size_t o = (size_t)v * 128 + 4 * ll;
    float4 xi = *(const float4*)&xin[o];
    float4 res;
    res.x = xi.x + fmaxf(g0.x, 0.f);
    res.y = xi.y + fmaxf(g0.y, 0.f);
    res.z = xi.z + fmaxf(g1.x, 0.f);
    res.w = xi.w + fmaxf(g1.y, 0.f);
    *(float4*)&out[o] = res;
}

extern "C" void kernel_launch(void* const* d_in, const int* in_sizes, int n_in,
                              void* d_out, int out_size, void* d_ws, size_t ws_size,
                              hipStream_t stream) {
    const float* x   = (const float*)d_in[0];
    const int*   ei  = (const int*)d_in[1];
    const float* ldt = (const float*)d_in[2];
    const float* llr = (const float*)d_in[3];
    const float* lim = (const float*)d_in[4];
    const float* W1  = (const float*)d_in[5];
    const float* W2  = (const float*)d_in[6];
    const float* Wp  = (const float*)d_in[7];
    const float* bp  = (const float*)d_in[8];
    float* out = (float*)d_out;

    const int N = in_sizes[0] / 128;
    const int E = in_sizes[1] / 2;
    const size_t nd = (size_t)N * 128;
    const int Mt = (N + 15) / 16;          // 16-row m-tiles
    const int Mt4 = (Mt + 3) / 4;          // 4 m-tiles per block
    const int NB = (N + 255) / 256;        // scan blocks

    ushort_t* xpb  = (ushort_t*)d_ws;      // all-bf16 node tables
    ushort_t* a1b  = xpb + nd;
    ushort_t* a2b  = a1b + nd;
    ushort_t* a3b  = a2b + nd;
    ushort_t* Xbb  = a3b + nd;
    ushort_t* ab1b = Xbb + nd;

    int*   cnt    = (int*)(ab1b + nd);     // N
    int*   off    = cnt + N;               // N+4 (padded)
    int*   cursor = off + N + 4;           // N
    float* bv     = (float*)(cursor + N);  // N
    float* Bv     = bv + N;                // N
    float* B2v    = Bv + N;                // N
    float* tab    = B2v + N;               // 512
    int*   bsum   = (int*)(tab + 512);     // NB
    int*   bpre   = bsum + NB;             // NB (NB even-padded below)
    uint2* csrb   = (uint2*)(bpre + NB + (NB & 1));  // E records, 8B-aligned
    ushort_t* wb1 = (ushort_t*)(csrb + E); // 32768
    ushort_t* wb2 = wb1 + 32768;           // 32768
    ushort_t* wpb = wb2 + 32768;           // 32768

    const int halfBlocks = (int)(((size_t)N * 32 + 255) / 256);
    const int eBlocks    = (E + 255) / 256;

    // init (zeros cnt + lambda tables)
    k_init<<<NB, 256, 0, stream>>>(ldt, llr, lim, tab, cnt, N);

    // bf16 weight prep (single launch) + MFMA MLP (4 m-tiles/block)
    k_prepw3<<<48, 256, 0, stream>>>(W1, W2, Wp, wb1, wb2, wpb);
    k_mlpf<<<Mt4, 256, 0, stream>>>(x, wb1, wb2, wpb, bp, xpb, Mt);

    // CSR build (hierarchical scan) + packed (src, bv[src]) edge records
    k_hist<<<eBlocks, 256, 0, stream>>>(ei, E, cnt);
    k_scanA<<<NB, 256, 0, stream>>>(cnt, N, bsum);
    k_scanB<<<1, 1024, 0, stream>>>(bsum, NB, bpre, &off[N]);
    k_scanC<<<NB, 256, 0, stream>>>(cnt, N, bpre, off, cursor, bv);
    k_fill<<<eBlocks, 256, 0, stream>>>(ei, E, bv, cursor, csrb);

    // fused gather + node passes (half-wave per node, uint2 loads, x4 unroll)
    k_passA<<<halfBlocks, 256, 0, stream>>>(xpb, csrb, off, tab, Xbb, a1b, N);
    k_passB<<<halfBlocks, 256, 0, stream>>>(xpb, a1b, csrb, off, tab, ab1b, Bv, B2v, a2b, N);
    k_passC<<<halfBlocks, 256, 0, stream>>>(xpb, a2b, a1b, Xbb, bv, Bv, csrb, off, tab, a3b, N);
    k_passD<<<halfBlocks, 256, 0, stream>>>(x, xpb, a3b, a2b, ab1b, bv, Bv, B2v, csrb, off, tab, out, N);
}

// Round 18
// 206.422 us; speedup vs baseline: 1.0154x; 1.0154x over previous
//
#include <hip/hip_runtime.h>

#define EPSF 1e-9f

typedef __bf16 bf16x8 __attribute__((ext_vector_type(8)));
typedef float  f32x4  __attribute__((ext_vector_type(4)));
typedef unsigned short ushort_t;
typedef unsigned int uint_t;
typedef ushort_t us8 __attribute__((ext_vector_type(8)));

__device__ __forceinline__ float2 cmul(float cr, float ci, float2 v) {
    return make_float2(cr * v.x - ci * v.y, ci * v.x + cr * v.y);
}

__device__ __forceinline__ ushort_t f2bf(float f) {
    unsigned int u = __float_as_uint(f);
    u += 0x7FFFu + ((u >> 16) & 1u);   // RNE
    return (ushort_t)(u >> 16);
}

__device__ __forceinline__ ushort_t f2bf_hw(float f) {   // native RNE cvt
    __bf16 b = (__bf16)f;
    return *(ushort_t*)&b;
}

// packed pair helpers: low 16 bits = element 2p, high = 2p+1
__device__ __forceinline__ float2 bfu2(uint_t u) {
    return make_float2(__uint_as_float(u << 16), __uint_as_float(u & 0xFFFF0000u));
}
__device__ __forceinline__ uint_t packbf(float2 v) {
    return ((uint_t)f2bf(v.y) << 16) | (uint_t)f2bf(v.x);
}

// ---------------- init: zero cnt + lambda tables (block 0) ----------------
__global__ void k_init(const float* __restrict__ ldt, const float* __restrict__ llr,
                       const float* __restrict__ lim, float* __restrict__ tab,
                       int* __restrict__ cnt, int N) {
    int i = blockIdx.x * blockDim.x + threadIdx.x;
    if (i < N) cnt[i] = 0;
    if (blockIdx.x == 0 && threadIdx.x < 64) {
        int p = threadIdx.x;
        float dt  = expf(ldt[0]);
        float mag = expf(-expf(llr[p]) * dt);
        float ph  = lim[p] * dt;
        float c = cosf(ph), s = sinf(ph);
        float m2 = mag * mag, m3 = m2 * mag;
        float c2 = c * c - s * s, s2 = 2.f * c * s;
        float c3 = c2 * c - s2 * s, s3 = s2 * c + c2 * s;
        tab[p]        = c * mag;          tab[64 + p]  = s * mag;          // L1
        tab[128 + p]  = c * (1.f - mag);  tab[192 + p] = s * (1.f - mag);  // O1
        tab[256 + p]  = c2 * m2;          tab[320 + p] = s2 * m2;          // L2
        tab[384 + p]  = c3 * m3;          tab[448 + p] = s3 * m3;          // L3
    }
}

// ---------------- prep: all 3 weights -> bf16 B-fragment layout, one launch ----------------
__global__ void k_prepw3(const float* __restrict__ W1, const float* __restrict__ W2,
                         const float* __restrict__ Wp, ushort_t* __restrict__ wb1,
                         ushort_t* __restrict__ wb2, ushort_t* __restrict__ wpb) {
    int tid = blockIdx.x * blockDim.x + threadIdx.x;
    const float* w; ushort_t* wb; int ncols, nsteps;
    if (tid < 4096)       { w = W1; wb = wb1; ncols = 256; nsteps = 4; }
    else if (tid < 8192)  { tid -= 4096; w = W2; wb = wb2; ncols = 256; nsteps = 4; }
    else                  { tid -= 8192; w = Wp; wb = wpb; ncols = 128; nsteps = 8; }
    int l  = tid & 63;
    int s  = (tid >> 6) % nsteps;
    int nt = tid / (64 * nsteps);
    int col = nt * 16 + (l & 15);
    int kb  = s * 32 + (l >> 4) * 8;
    us8 d;
#pragma unroll
    for (int j = 0; j < 8; ++j) d[j] = f2bf(w[(size_t)(kb + j) * ncols + col]);
    *(us8*)(wb + (size_t)tid * 8) = d;
}

// ---------------- MFMA fused MLP -> bf16 xpb (round-16 structure: 2 m-tiles/block, 16KB LDS) ----------------
__global__ void __launch_bounds__(256)
k_mlpf(const float* __restrict__ x, const ushort_t* __restrict__ wb1,
       const ushort_t* __restrict__ wb2, const ushort_t* __restrict__ wpb,
       const float* __restrict__ bp, ushort_t* __restrict__ xpb, int Mt) {
    __shared__ ushort_t hs[2][4096];   // 16KB: per-mtile 16x256 bf16 H (swizzled), block-shared
    const int wid = threadIdx.x >> 6, l = threadIdx.x & 63;
    const int mt0 = blockIdx.x * 2;
    const bool has1 = (mt0 + 1) < Mt;
    const int llo = l & 15, lhi = l >> 4;

    bf16x8 af[2][4];
#pragma unroll
    for (int m = 0; m < 2; ++m) {
        int mt = (m == 1 && !has1) ? mt0 : (mt0 + m);   // clamp tail
        const float* xr = x + (size_t)(mt * 16 + llo) * 128 + lhi * 8;
#pragma unroll
        for (int s = 0; s < 4; ++s) {
            float4 v0 = *(const float4*)(xr + s * 32);
            float4 v1 = *(const float4*)(xr + s * 32 + 4);
            __bf16 d[8];
            d[0] = (__bf16)v0.x; d[1] = (__bf16)v0.y; d[2] = (__bf16)v0.z; d[3] = (__bf16)v0.w;
            d[4] = (__bf16)v1.x; d[5] = (__bf16)v1.y; d[6] = (__bf16)v1.z; d[7] = (__bf16)v1.w;
            af[m][s] = *(bf16x8*)d;
        }
    }

    const bf16x8* B1 = (const bf16x8*)wb1;
    const bf16x8* B2 = (const bf16x8*)wb2;
    const bf16x8* BP = (const bf16x8*)wpb;
    const f32x4 zero = {0.f, 0.f, 0.f, 0.f};

    // ---- Phase 1: GEMM1/2 + silu; wave w owns nt = 4w..4w+3 ----
#pragma unroll
    for (int j = 0; j < 4; ++j) {
        int nt = wid * 4 + j;
        bf16x8 b1[4], b2[4];
#pragma unroll
        for (int s = 0; s < 4; ++s) {
            b1[s] = B1[(nt * 4 + s) * 64 + l];
            b2[s] = B2[(nt * 4 + s) * 64 + l];
        }
#pragma unroll
        for (int m = 0; m < 2; ++m) {
            f32x4 a1 = zero, a2 = zero;
#pragma unroll
            for (int s = 0; s < 4; ++s) {
                a1 = __builtin_amdgcn_mfma_f32_16x16x32_bf16(af[m][s], b1[s], a1, 0, 0, 0);
                a2 = __builtin_amdgcn_mfma_f32_16x16x32_bf16(af[m][s], b2[s], a2, 0, 0, 0);
            }
#pragma unroll
            for (int i = 0; i < 4; ++i) {
                float g = a1[i];
                float hv = g * __builtin_amdgcn_rcpf(1.f + __expf(-g)) * a2[i];
                int r = 4 * lhi + i;
                int byte = (r << 9) + ((nt * 16 + llo) << 1);  // row stride 512B (256 bf16)
                byte ^= (r & 7) << 4;
                hs[m][byte >> 1] = f2bf_hw(hv);
            }
        }
    }
    __syncthreads();

    // ---- Phase 2: GEMM3 over K=256; wave w owns nt3 = 2w, 2w+1 ----
#pragma unroll
    for (int j = 0; j < 2; ++j) {
        int nt3 = wid * 2 + j;
        f32x4 acc0 = zero, acc1 = zero;
#pragma unroll
        for (int sg = 0; sg < 8; ++sg) {
            bf16x8 bw = BP[(nt3 * 8 + sg) * 64 + l];
            int byte = (llo << 9) + (sg << 6) + (lhi << 4);
            byte ^= (llo & 7) << 4;
            bf16x8 h0 = *(const bf16x8*)((const char*)hs[0] + byte);
            acc0 = __builtin_amdgcn_mfma_f32_16x16x32_bf16(h0, bw, acc0, 0, 0, 0);
            bf16x8 h1 = *(const bf16x8*)((const char*)hs[1] + byte);
            acc1 = __builtin_amdgcn_mfma_f32_16x16x32_bf16(h1, bw, acc1, 0, 0, 0);
        }
        float bpv = bp[nt3 * 16 + llo];
        {
            const int row0 = mt0 * 16;
#pragma unroll
            for (int i = 0; i < 4; ++i) {
                int r = row0 + 4 * lhi + i;
                xpb[(size_t)r * 128 + nt3 * 16 + llo] = f2bf_hw(acc0[i] + bpv);
            }
        }
        if (has1) {
            const int row0 = (mt0 + 1) * 16;
#pragma unroll
            for (int i = 0; i < 4; ++i) {
                int r = row0 + 4 * lhi + i;
                xpb[(size_t)r * 128 + nt3 * 16 + llo] = f2bf_hw(acc1[i] + bpv);
            }
        }
    }
}

// ---------------- CSR build (by dst). in-deg == out-deg for this edge list ----------------
__global__ void k_hist(const int* __restrict__ ei, int E, int* __restrict__ cnt) {
    int e = blockIdx.x * blockDim.x + threadIdx.x;
    if (e < E) atomicAdd(&cnt[ei[E + e]], 1);      // histogram over dst
}

__global__ void __launch_bounds__(256)
k_scanA(const int* __restrict__ cnt, int N, int* __restrict__ bsum) {
    __shared__ int s[256];
    int t = threadIdx.x;
    int i = blockIdx.x * 256 + t;
    int v = (i < N) ? cnt[i] : 0;
    s[t] = v;
    __syncthreads();
#pragma unroll
    for (int d = 128; d > 0; d >>= 1) {
        if (t < d) s[t] += s[t + d];
        __syncthreads();
    }
    if (t == 0) bsum[blockIdx.x] = s[0];
}

__global__ void __launch_bounds__(1024)
k_scanB(const int* __restrict__ bsum, int NB, int* __restrict__ bpre,
        int* __restrict__ offN) {
    __shared__ int s[1024];
    int t = threadIdx.x;
    int v = (t < NB) ? bsum[t] : 0;
    s[t] = v;
    __syncthreads();
    for (int d = 1; d < 1024; d <<= 1) {
        int u = (t >= d) ? s[t - d] : 0;
        __syncthreads();
        s[t] += u;
        __syncthreads();
    }
    if (t < NB) bpre[t] = s[t] - v;          // exclusive
    if (t == NB - 1) *offN = s[t];           // total
}

__global__ void __launch_bounds__(256)
k_scanC(const int* __restrict__ cnt, int N, const int* __restrict__ bpre,
        int* __restrict__ off, int* __restrict__ cursor, float* __restrict__ bv) {
    __shared__ int s[256];
    int t = threadIdx.x;
    int i = blockIdx.x * 256 + t;
    int v = (i < N) ? cnt[i] : 0;
    s[t] = v;
    __syncthreads();
    for (int d = 1; d < 256; d <<= 1) {
        int u = (t >= d) ? s[t - d] : 0;
        __syncthreads();
        s[t] += u;
        __syncthreads();
    }
    if (i < N) {
        int excl = bpre[blockIdx.x] + s[t] - v;
        off[i] = excl;
        cursor[i] = excl;
        bv[i] = (v > 1) ? (-1.f / ((float)v - 1.f + EPSF)) : 0.f;
    }
}

// fill packed edge records: (src, bv[src]) -> one 8B load per edge in the passes
__global__ void k_fill(const int* __restrict__ ei, int E, const float* __restrict__ bv,
                       int* __restrict__ cursor, uint2* __restrict__ csrb) {
    int e = blockIdx.x * blockDim.x + threadIdx.x;
    if (e < E) {
        int s = ei[e], d = ei[E + e];
        int p = atomicAdd(&cursor[d], 1);
        csrb[p] = make_uint2((uint_t)s, __float_as_uint(bv[s]));
    }
}

// ---------------- fused gather + node passes (HALF-WAVE per node, uint2 loads, x4 unroll) ----------------
// lane ll in [0,32): owns complex pairs p0=2*ll, p1=2*ll+1 (uint2 per table row).

__global__ void __launch_bounds__(256)
k_passA(const ushort_t* __restrict__ xpb, const uint2* __restrict__ eb,
        const int* __restrict__ off, const float* __restrict__ tab,
        ushort_t* __restrict__ Xbb, ushort_t* __restrict__ a1b, int N) {
    int tid = blockIdx.x * blockDim.x + threadIdx.x;
    int v = tid >> 5, ll = tid & 31;
    if (v >= N) return;
    int beg = off[v], end = off[v + 1];
    float2 m00 = {0.f,0.f}, m01 = {0.f,0.f}, xb0 = {0.f,0.f}, xb1 = {0.f,0.f};
    const uint2* tb = (const uint2*)xpb;   // row stride 32 uint2
    int k = beg;
    for (; k + 3 < end; k += 4) {
        uint2 e0 = eb[k], e1 = eb[k+1], e2 = eb[k+2], e3 = eb[k+3];
        uint2 u0 = tb[(size_t)e0.x * 32 + ll];
        uint2 u1 = tb[(size_t)e1.x * 32 + ll];
        uint2 u2 = tb[(size_t)e2.x * 32 + ll];
        uint2 u3 = tb[(size_t)e3.x * 32 + ll];
        float b0 = __uint_as_float(e0.y), b1 = __uint_as_float(e1.y);
        float b2 = __uint_as_float(e2.y), b3 = __uint_as_float(e3.y);
        float2 t00=bfu2(u0.x), t01=bfu2(u0.y), t10=bfu2(u1.x), t11=bfu2(u1.y);
        float2 t20=bfu2(u2.x), t21=bfu2(u2.y), t30=bfu2(u3.x), t31=bfu2(u3.y);
        m00.x += (t00.x+t10.x)+(t20.x+t30.x); m00.y += (t00.y+t10.y)+(t20.y+t30.y);
        m01.x += (t01.x+t11.x)+(t21.x+t31.x); m01.y += (t01.y+t11.y)+(t21.y+t31.y);
        xb0.x += b0*t00.x + b1*t10.x + b2*t20.x + b3*t30.x;
        xb0.y += b0*t00.y + b1*t10.y + b2*t20.y + b3*t30.y;
        xb1.x += b0*t01.x + b1*t11.x + b2*t21.x + b3*t31.x;
        xb1.y += b0*t01.y + b1*t11.y + b2*t21.y + b3*t31.y;
    }
    for (; k < end; ++k) {
        uint2 e0 = eb[k];
        uint2 u0 = tb[(size_t)e0.x * 32 + ll];
        float b0 = __uint_as_float(e0.y);
        float2 t00=bfu2(u0.x), t01=bfu2(u0.y);
        m00.x += t00.x; m00.y += t00.y; m01.x += t01.x; m01.y += t01.y;
        xb0.x += b0*t00.x; xb0.y += b0*t00.y;
        xb1.x += b0*t01.x; xb1.y += b0*t01.y;
    }
    ((uint2*)Xbb)[(size_t)v * 32 + ll] = make_uint2(packbf(xb0), packbf(xb1));
    uint2 xvu = tb[(size_t)v * 32 + ll];
    float2 xv0 = bfu2(xvu.x), xv1 = bfu2(xvu.y);
    int dg = end - beg;
    int p0 = 2 * ll, p1 = p0 + 1;
    float Q = 1.f / ((float)dg - 1.f + EPSF);
    float2 a0, a1v;
    {
        float L1r=tab[p0], L1i=tab[64+p0], O1r=tab[128+p0], O1i=tab[192+p0];
        float2 t1 = cmul(O1r,O1i,xv0), t2 = cmul(L1r,L1i,m00);
        a0 = make_float2(t1.x + Q*t2.x, t1.y + Q*t2.y);
        if (dg == 1) a0 = xv0;
    }
    {
        float L1r=tab[p1], L1i=tab[64+p1], O1r=tab[128+p1], O1i=tab[192+p1];
        float2 t1 = cmul(O1r,O1i,xv1), t2 = cmul(L1r,L1i,m01);
        a1v = make_float2(t1.x + Q*t2.x, t1.y + Q*t2.y);
        if (dg == 1) a1v = xv1;
    }
    ((uint2*)a1b)[(size_t)v * 32 + ll] = make_uint2(packbf(a0), packbf(a1v));
}

__global__ void __launch_bounds__(256)
k_passB(const ushort_t* __restrict__ xpb, const ushort_t* __restrict__ a1b,
        const uint2* __restrict__ eb, const int* __restrict__ off,
        const float* __restrict__ tab, ushort_t* __restrict__ ab1b,
        float* __restrict__ Bv, float* __restrict__ B2v,
        ushort_t* __restrict__ a2b, int N) {
    int tid = blockIdx.x * blockDim.x + threadIdx.x;
    int v = tid >> 5, ll = tid & 31;
    if (v >= N) return;
    int beg = off[v], end = off[v + 1];
    float2 A10 = {0.f,0.f}, A11 = {0.f,0.f}, ab0 = {0.f,0.f}, ab1 = {0.f,0.f};
    float Bs = 0.f, B2s = 0.f;
    const uint2* tb = (const uint2*)a1b;
    int k = beg;
    for (; k + 3 < end; k += 4) {
        uint2 e0 = eb[k], e1 = eb[k+1], e2 = eb[k+2], e3 = eb[k+3];
        uint2 u0 = tb[(size_t)e0.x * 32 + ll];
        uint2 u1 = tb[(size_t)e1.x * 32 + ll];
        uint2 u2 = tb[(size_t)e2.x * 32 + ll];
        uint2 u3 = tb[(size_t)e3.x * 32 + ll];
        float b0 = __uint_as_float(e0.y), b1 = __uint_as_float(e1.y);
        float b2 = __uint_as_float(e2.y), b3 = __uint_as_float(e3.y);
        float2 t00=bfu2(u0.x), t01=bfu2(u0.y), t10=bfu2(u1.x), t11=bfu2(u1.y);
        float2 t20=bfu2(u2.x), t21=bfu2(u2.y), t30=bfu2(u3.x), t31=bfu2(u3.y);
        A10.x += (t00.x+t10.x)+(t20.x+t30.x); A10.y += (t00.y+t10.y)+(t20.y+t30.y);
        A11.x += (t01.x+t11.x)+(t21.x+t31.x); A11.y += (t01.y+t11.y)+(t21.y+t31.y);
        ab0.x += b0*t00.x + b1*t10.x + b2*t20.x + b3*t30.x;
        ab0.y += b0*t00.y + b1*t10.y + b2*t20.y + b3*t30.y;
        ab1.x += b0*t01.x + b1*t11.x + b2*t21.x + b3*t31.x;
        ab1.y += b0*t01.y + b1*t11.y + b2*t21.y + b3*t31.y;
        Bs += (b0 + b1) + (b2 + b3);
        B2s += (b0*b0 + b1*b1) + (b2*b2 + b3*b3);
    }
    for (; k < end; ++k) {
        uint2 e0 = eb[k];
        uint2 u0 = tb[(size_t)e0.x * 32 + ll];
        float b0 = __uint_as_float(e0.y);
        float2 t00=bfu2(u0.x), t01=bfu2(u0.y);
        A10.x += t00.x; A10.y += t00.y; A11.x += t01.x; A11.y += t01.y;
        ab0.x += b0*t00.x; ab0.y += b0*t00.y;
        ab1.x += b0*t01.x; ab1.y += b0*t01.y;
        Bs += b0; B2s += b0*b0;
    }
    ((uint2*)ab1b)[(size_t)v * 32 + ll] = make_uint2(packbf(ab0), packbf(ab1));
    if (ll == 0) { Bv[v] = Bs; B2v[v] = B2s; }
    uint2 xvu = ((const uint2*)xpb)[(size_t)v * 32 + ll];
    float2 xv0 = bfu2(xvu.x), xv1 = bfu2(xvu.y);
    int dg = end - beg;
    int p0 = 2 * ll, p1 = p0 + 1;
    float Q = 1.f / ((float)dg - 1.f + EPSF);
    float2 a0, a1v;
    {
        float L1r=tab[p0], L1i=tab[64+p0], O1r=tab[128+p0], O1i=tab[192+p0];
        float2 lx = cmul(L1r,L1i,xv0);
        float2 m1 = make_float2(A10.x + Bs*lx.x, A10.y + Bs*lx.y);
        float2 t1 = cmul(O1r,O1i,xv0), lm = cmul(L1r,L1i,m1);
        a0 = make_float2(t1.x + Q*lm.x, t1.y + Q*lm.y);
        if (dg == 1) a0 = xv0;
    }
    {
        float L1r=tab[p1], L1i=tab[64+p1], O1r=tab[128+p1], O1i=tab[192+p1];
        float2 lx = cmul(L1r,L1i,xv1);
        float2 m1 = make_float2(A11.x + Bs*lx.x, A11.y + Bs*lx.y);
        float2 t1 = cmul(O1r,O1i,xv1), lm = cmul(L1r,L1i,m1);
        a1v = make_float2(t1.x + Q*lm.x, t1.y + Q*lm.y);
        if (dg == 1) a1v = xv1;
    }
    ((uint2*)a2b)[(size_t)v * 32 + ll] = make_uint2(packbf(a0), packbf(a1v));
}

__global__ void __launch_bounds__(256)
k_passC(const ushort_t* __restrict__ xpb, const ushort_t* __restrict__ a2b,
        const ushort_t* __restrict__ a1b, const ushort_t* __restrict__ Xbb,
        const float* __restrict__ bv, const float* __restrict__ Bv,
        const uint2* __restrict__ eb, const int* __restrict__ off,
        const float* __restrict__ tab, ushort_t* __restrict__ a3b, int N) {
    int tid = blockIdx.x * blockDim.x + threadIdx.x;
    int v = tid >> 5, ll = tid & 31;
    if (v >= N) return;
    int beg = off[v], end = off[v + 1];
    float2 A20 = {0.f,0.f}, A21 = {0.f,0.f};
    const uint2* tb = (const uint2*)a2b;
    int k = beg;
    for (; k + 3 < end; k += 4) {
        uint2 u0 = tb[(size_t)eb[k].x * 32 + ll];
        uint2 u1 = tb[(size_t)eb[k+1].x * 32 + ll];
        uint2 u2 = tb[(size_t)eb[k+2].x * 32 + ll];
        uint2 u3 = tb[(size_t)eb[k+3].x * 32 + ll];
        float2 t00=bfu2(u0.x), t01=bfu2(u0.y), t10=bfu2(u1.x), t11=bfu2(u1.y);
        float2 t20=bfu2(u2.x), t21=bfu2(u2.y), t30=bfu2(u3.x), t31=bfu2(u3.y);
        A20.x += (t00.x+t10.x)+(t20.x+t30.x); A20.y += (t00.y+t10.y)+(t20.y+t30.y);
        A21.x += (t01.x+t11.x)+(t21.x+t31.x); A21.y += (t01.y+t11.y)+(t21.y+t31.y);
    }
    for (; k < end; ++k) {
        uint2 u0 = tb[(size_t)eb[k].x * 32 + ll];
        float2 t00=bfu2(u0.x), t01=bfu2(u0.y);
        A20.x += t00.x; A20.y += t00.y; A21.x += t01.x; A21.y += t01.y;
    }
    size_t vo = (size_t)v * 32 + ll;
    uint2 xvu = ((const uint2*)xpb)[vo];
    uint2 a1u = ((const uint2*)a1b)[vo];
    uint2 xbu = ((const uint2*)Xbb)[vo];
    float2 xv0 = bfu2(xvu.x), xv1 = bfu2(xvu.y);
    float2 a10 = bfu2(a1u.x), a11 = bfu2(a1u.y);
    float2 Xb0 = bfu2(xbu.x), Xb1 = bfu2(xbu.y);
    int dg = end - beg;
    float Bs = Bv[v], bs = bv[v];
    int p0 = 2 * ll, p1 = p0 + 1;
    float Q = 1.f / ((float)dg - 1.f + EPSF);
    float2 a0, a1vv;
    {
        float L1r=tab[p0], L1i=tab[64+p0], O1r=tab[128+p0], O1i=tab[192+p0];
        float L2r=tab[256+p0], L2i=tab[320+p0];
        float2 la1 = cmul(L1r,L1i,a10), lxb = cmul(L2r,L2i,Xb0);
        float2 m2 = make_float2(A20.x + Bs*la1.x + bs*lxb.x,
                                A20.y + Bs*la1.y + bs*lxb.y);
        float2 t1 = cmul(O1r,O1i,xv0), lm = cmul(L1r,L1i,m2);
        a0 = make_float2(t1.x + Q*lm.x, t1.y + Q*lm.y);
        if (dg == 1) a0 = xv0;
    }
    {
        float L1r=tab[p1], L1i=tab[64+p1], O1r=tab[128+p1], O1i=tab[192+p1];
        float L2r=tab[256+p1], L2i=tab[320+p1];
        float2 la1 = cmul(L1r,L1i,a11), lxb = cmul(L2r,L2i,Xb1);
        float2 m2 = make_float2(A21.x + Bs*la1.x + bs*lxb.x,
                                A21.y + Bs*la1.y + bs*lxb.y);
        float2 t1 = cmul(O1r,O1i,xv1), lm = cmul(L1r,L1i,m2);
        a1vv = make_float2(t1.x + Q*lm.x, t1.y + Q*lm.y);
        if (dg == 1) a1vv = xv1;
    }
    ((uint2*)a3b)[vo] = make_uint2(packbf(a0), packbf(a1vv));
}

__global__ void __launch_bounds__(256)
k_passD(const float* __restrict__ xin, const ushort_t* __restrict__ xpb,
        const ushort_t* __restrict__ a3b, const ushort_t* __restrict__ a2b,
        const ushort_t* __restrict__ ab1b, const float* __restrict__ bv,
        const float* __restrict__ Bv, const float* __restrict__ B2v,
        const uint2* __restrict__ eb, const int* __restrict__ off,
        const float* __restrict__ tab, float* __restrict__ out, int N) {
    int tid = blockIdx.x * blockDim.x + threadIdx.x;
    int v = tid >> 5, ll = tid & 31;
    if (v >= N) return;
    int beg = off[v], end = off[v + 1];
    float2 A30 = {0.f,0.f}, A31 = {0.f,0.f};
    const uint2* tb = (const uint2*)a3b;
    int k = beg;
    for (; k + 3 < end; k += 4) {
        uint2 u0 = tb[(size_t)eb[k].x * 32 + ll];
        uint2 u1 = tb[(size_t)eb[k+1].x * 32 + ll];
        uint2 u2 = tb[(size_t)eb[k+2].x * 32 + ll];
        uint2 u3 = tb[(size_t)eb[k+3].x * 32 + ll];
        float2 t00=bfu2(u0.x), t01=bfu2(u0.y), t10=bfu2(u1.x), t11=bfu2(u1.y);
        float2 t20=bfu2(u2.x), t21=bfu2(u2.y), t30=bfu2(u3.x), t31=bfu2(u3.y);
        A30.x += (t00.x+t10.x)+(t20.x+t30.x); A30.y += (t00.y+t10.y)+(t20.y+t30.y);
        A31.x += (t01.x+t11.x)+(t21.x+t31.x); A31.y += (t01.y+t11.y)+(t21.y+t31.y);
    }
    for (; k < end; ++k) {
        uint2 u0 = tb[(size_t)eb[k].x * 32 + ll];
        float2 t00=bfu2(u0.x), t01=bfu2(u0.y);
        A30.x += t00.x; A30.y += t00.y; A31.x += t01.x; A31.y += t01.y;
    }
    size_t vo = (size_t)v * 32 + ll;
    uint2 xvu = ((const uint2*)xpb)[vo];
    uint2 a2u = ((const uint2*)a2b)[vo];
    uint2 abu = ((const uint2*)ab1b)[vo];
    float2 xv0 = bfu2(xvu.x), xv1 = bfu2(xvu.y);
    float2 a20 = bfu2(a2u.x), a21 = bfu2(a2u.y);
    float2 Ab0 = bfu2(abu.x), Ab1v = bfu2(abu.y);
    int dg = end - beg;
    float Bs = Bv[v], bs = bv[v], B2s = B2v[v];
    float bB2 = bs * B2s;
    int p0 = 2 * ll, p1 = p0 + 1;
    float2 g0, g1;
    {
        float L1r=tab[p0], L1i=tab[64+p0], O1r=tab[128+p0], O1i=tab[192+p0];
        float L2r=tab[256+p0], L2i=tab[320+p0], L3r=tab[384+p0], L3i=tab[448+p0];
        float2 la2 = cmul(L1r,L1i,a20), lab = cmul(L2r,L2i,Ab0), lx3 = cmul(L3r,L3i,xv0);
        float2 m3 = make_float2(A30.x + Bs*la2.x + bs*lab.x + bB2*lx3.x,
                                A30.y + Bs*la2.y + bs*lab.y + bB2*lx3.y);
        if (dg == 0) {
            g0 = xv0;
        } else {
            float inv = 1.f / ((float)dg + EPSF);
            float2 t1 = cmul(O1r,O1i,xv0), lm = cmul(L1r,L1i,m3);
            g0 = make_float2(t1.x + lm.x*inv, t1.y + lm.y*inv);
        }
    }
    {
        float L1r=tab[p1], L1i=tab[64+p1], O1r=tab[128+p1], O1i=tab[192+p1];
        float L2r=tab[256+p1], L2i=tab[320+p1], L3r=tab[384+p1], L3i=tab[448+p1];
        float2 la2 = cmul(L1r,L1i,a21), lab = cmul(L2r,L2i,Ab1v), lx3 = cmul(L3r,L3i,xv1);
        float2 m3 = make_float2(A31.x + Bs*la2.x + bs*lab.x + bB2*lx3.x,
                                A31.y + Bs*la2.y + bs*lab.y + bB2*lx3.y);
        if (dg == 0) {
            g1 = xv1;
        } else {
            float inv = 1.f / ((float)dg + EPSF);
            float2 t1 = cmul(O1r,O1i,xv1), lm = cmul(L1r,L1i,m3);
            g1 = make_float2(t1.x + lm.x*inv, t1.y + lm.y*inv);
        }
    }
    size_t o = (size_t)v * 128 + 4 * ll;
    float4 xi = *(const float4*)&xin[o];
    float4 res;
    res.x = xi.x + fmaxf(g0.x, 0.f);
    res.y = xi.y + fmaxf(g0.y, 0.f);
    res.z = xi.z + fmaxf(g1.x, 0.f);
    res.w = xi.w + fmaxf(g1.y, 0.f);
    *(float4*)&out[o] = res;
}

extern "C" void kernel_launch(void* const* d_in, const int* in_sizes, int n_in,
                              void* d_out, int out_size, void* d_ws, size_t ws_size,
                              hipStream_t stream) {
    const float* x   = (const float*)d_in[0];
    const int*   ei  = (const int*)d_in[1];
    const float* ldt = (const float*)d_in[2];
    const float* llr = (const float*)d_in[3];
    const float* lim = (const float*)d_in[4];
    const float* W1  = (const float*)d_in[5];
    const float* W2  = (const float*)d_in[6];
    const float* Wp  = (const float*)d_in[7];
    const float* bp  = (const float*)d_in[8];
    float* out = (float*)d_out;

    const int N = in_sizes[0] / 128;
    const int E = in_sizes[1] / 2;
    const size_t nd = (size_t)N * 128;
    const int Mt = (N + 15) / 16;          // 16-row m-tiles
    const int Mt2 = (Mt + 1) / 2;          // m-tile pairs (one block each)
    const int NB = (N + 255) / 256;        // scan blocks

    ushort_t* xpb  = (ushort_t*)d_ws;      // all-bf16 node tables
    ushort_t* a1b  = xpb + nd;
    ushort_t* a2b  = a1b + nd;
    ushort_t* a3b  = a2b + nd;
    ushort_t* Xbb  = a3b + nd;
    ushort_t* ab1b = Xbb + nd;

    int*   cnt    = (int*)(ab1b + nd);     // N
    int*   off    = cnt + N;               // N+4 (padded)
    int*   cursor = off + N + 4;           // N
    float* bv     = (float*)(cursor + N);  // N
    float* Bv     = bv + N;                // N
    float* B2v    = Bv + N;                // N
    float* tab    = B2v + N;               // 512
    int*   bsum   = (int*)(tab + 512);     // NB
    int*   bpre   = bsum + NB;             // NB (NB even-padded below)
    uint2* csrb   = (uint2*)(bpre + NB + (NB & 1));  // E records, 8B-aligned
    ushort_t* wb1 = (ushort_t*)(csrb + E); // 32768
    ushort_t* wb2 = wb1 + 32768;           // 32768
    ushort_t* wpb = wb2 + 32768;           // 32768

    const int halfBlocks = (int)(((size_t)N * 32 + 255) / 256);
    const int eBlocks    = (E + 255) / 256;

    // init (zeros cnt + lambda tables)
    k_init<<<NB, 256, 0, stream>>>(ldt, llr, lim, tab, cnt, N);

    // bf16 weight prep (single launch) + MFMA MLP (round-16 structure)
    k_prepw3<<<48, 256, 0, stream>>>(W1, W2, Wp, wb1, wb2, wpb);
    k_mlpf<<<Mt2, 256, 0, stream>>>(x, wb1, wb2, wpb, bp, xpb, Mt);

    // CSR build (hierarchical scan) + packed (src, bv[src]) edge records
    k_hist<<<eBlocks, 256, 0, stream>>>(ei, E, cnt);
    k_scanA<<<NB, 256, 0, stream>>>(cnt, N, bsum);
    k_scanB<<<1, 1024, 0, stream>>>(bsum, NB, bpre, &off[N]);
    k_scanC<<<NB, 256, 0, stream>>>(cnt, N, bpre, off, cursor, bv);
    k_fill<<<eBlocks, 256, 0, stream>>>(ei, E, bv, cursor, csrb);

    // fused gather + node passes (half-wave per node, uint2 loads, x4 unroll)
    k_passA<<<halfBlocks, 256, 0, stream>>>(xpb, csrb, off, tab, Xbb, a1b, N);
    k_passB<<<halfBlocks, 256, 0, stream>>>(xpb, a1b, csrb, off, tab, ab1b, Bv, B2v, a2b, N);
    k_passC<<<halfBlocks, 256, 0, stream>>>(xpb, a2b, a1b, Xbb, bv, Bv, csrb, off, tab, a3b, N);
    k_passD<<<halfBlocks, 256, 0, stream>>>(x, xpb, a3b, a2b, ab1b, bv, Bv, B2v, csrb, off, tab, out, N);
}